// Round 1
// baseline (448.108 us; speedup 1.0000x reference)
//
#include <hip/hip_runtime.h>

#define N_R   256
#define N_HOP 3
#define N_E   200000
#define N_T   1000000
#define B     32
#define D_Q   768
#define D_IN  1280   // D_Q + 2*N_R

// ---------------------------------------------------------------------------
// Transpose x (B, N_E) -> xT (N_E, B) via LDS tile (64 entities x 32 batch).
// ---------------------------------------------------------------------------
__global__ void k_transpose_in(const float* __restrict__ x, float* __restrict__ xT) {
    __shared__ float tile[64 * 33];
    int e0 = blockIdx.x * 64;
    int t  = threadIdx.x;
#pragma unroll
    for (int i = 0; i < 8; ++i) {
        int o = i * 256 + t;          // 0..2047
        int b = o >> 6, e = o & 63;   // read x row-major, coalesced per row
        tile[e * 33 + b] = x[b * N_E + e0 + e];
    }
    __syncthreads();
#pragma unroll
    for (int i = 0; i < 8; ++i) {
        int o = i * 256 + t;
        int e = o >> 5, b = o & 31;   // write xT contiguous
        xT[(e0 + e) * 32 + b] = tile[e * 33 + b];
    }
}

// ---------------------------------------------------------------------------
// r0[rel,b] = dot(W_inf[rel, 0:768], h_q[b, :])   -> rT0 in (N_R, B) layout
// ---------------------------------------------------------------------------
__global__ void k_r0(const float* __restrict__ h_q, const float* __restrict__ W_inf,
                     float* __restrict__ rT0) {
    __shared__ float hs[32 * 129];
    int t   = threadIdx.x;
    int idx = blockIdx.x * 256 + t;
    int rel = idx >> 5, b = idx & 31;
    float acc = 0.f;
    for (int k0 = 0; k0 < D_Q; k0 += 128) {
#pragma unroll
        for (int i = 0; i < 16; ++i) {
            int o = i * 256 + t;            // 0..4095
            int bb = o >> 7, k = o & 127;   // coalesced h_q chunk load
            hs[bb * 129 + k] = h_q[bb * D_Q + k0 + k];
        }
        __syncthreads();
        const float* w = &W_inf[rel * D_IN + k0];
#pragma unroll 8
        for (int k = 0; k < 128; ++k)
            acc += w[k] * hs[b * 129 + k];
        __syncthreads();
    }
    rT0[rel * 32 + b] = acc;
}

// ---------------------------------------------------------------------------
// r_h = rT0(base, h_q part) + W2 @ r_{h-1} (+ W3 @ r0 if hop==2)
// ---------------------------------------------------------------------------
__global__ void k_r12(const float* __restrict__ W_inf, const float* __restrict__ rT0,
                      const float* __restrict__ rPrev, float* __restrict__ rOut,
                      int hop2) {
    int idx = blockIdx.x * 256 + threadIdx.x;
    int rel = idx >> 5, b = idx & 31;
    float acc = rT0[rel * 32 + b];
    const float* w2 = &W_inf[rel * D_IN + D_Q];
    for (int j = 0; j < N_R; ++j)
        acc += w2[j] * rPrev[j * 32 + b];
    if (hop2) {
        const float* w3 = &W_inf[rel * D_IN + D_Q + N_R];
        for (int j = 0; j < N_R; ++j)
            acc += w3[j] * rT0[j * 32 + b];
    }
    rOut[rel * 32 + b] = acc;
}

// ---------------------------------------------------------------------------
// c0..c2 per batch row, softmax over hops -> a_w[hop*32 + b]
// ---------------------------------------------------------------------------
__global__ void k_att(const float* __restrict__ h_q, const float* __restrict__ W_att,
                      const float* __restrict__ rT0, const float* __restrict__ rT1,
                      float* __restrict__ a_w) {
    int b = threadIdx.x;   // 32 threads
    float c0 = 0.f;
    for (int k = 0; k < D_Q; ++k) c0 += W_att[k] * h_q[b * D_Q + k];
    float s1 = 0.f, s2 = 0.f, s3 = 0.f;
    for (int j = 0; j < N_R; ++j) {
        float w2 = W_att[D_Q + j];
        float w3 = W_att[D_Q + N_R + j];
        float r0v = rT0[j * 32 + b];
        float r1v = rT1[j * 32 + b];
        s1 += w2 * r0v;
        s2 += w2 * r1v;
        s3 += w3 * r0v;
    }
    float c1 = c0 + s1;
    float c2 = c0 + s2 + s3;
    float m  = fmaxf(c0, fmaxf(c1, c2));
    float e0 = __expf(c0 - m), e1 = __expf(c1 - m), e2 = __expf(c2 - m);
    float inv = 1.f / (e0 + e1 + e2);
    a_w[0 * 32 + b] = e0 * inv;
    a_w[1 * 32 + b] = e1 * inv;
    a_w[2 * 32 + b] = e2 * inv;
}

// ---------------------------------------------------------------------------
// One hop: for each triple t, xN[obj_t, b] += xT[subj_t, b] * rT[rel_t, b].
// 32-lane group per triple; skip atomic (and rel load) where x value is 0.
// ---------------------------------------------------------------------------
__global__ void k_hop(const float* __restrict__ xT, const float* __restrict__ rT,
                      const int* __restrict__ subj, const int* __restrict__ rel,
                      const int* __restrict__ obj, float* __restrict__ xN) {
    int p = blockIdx.x * 256 + threadIdx.x;
    int t = p >> 5;
    int b = p & 31;
    if (t >= N_T) return;
    int s   = subj[t];
    float v = xT[s * 32 + b];
    if (v != 0.f) {
        float rv = rT[rel[t] * 32 + b];
        unsafeAtomicAdd(&xN[obj[t] * 32 + b], v * rv);
    }
}

// ---------------------------------------------------------------------------
// out(B,N_E) (+)= a[hop,b] * xT(N_E,B), transposing via LDS tile.
// ---------------------------------------------------------------------------
__global__ void k_axpy(const float* __restrict__ xT, const float* __restrict__ a_w,
                       int hop, float* __restrict__ out, int store) {
    __shared__ float tile[32 * 65];
    int e0 = blockIdx.x * 64;
    int t  = threadIdx.x;
#pragma unroll
    for (int i = 0; i < 8; ++i) {
        int o = i * 256 + t;
        int e = o >> 5, b = o & 31;   // contiguous read of xT
        tile[b * 65 + e] = xT[(e0 + e) * 32 + b];
    }
    __syncthreads();
#pragma unroll
    for (int i = 0; i < 8; ++i) {
        int o = i * 256 + t;
        int b = o >> 6, e = o & 63;   // coalesced write per out row segment
        float v = a_w[hop * 32 + b] * tile[b * 65 + e];
        int oi = b * N_E + e0 + e;
        if (store) out[oi] = v;
        else       out[oi] += v;
    }
}

extern "C" void kernel_launch(void* const* d_in, const int* in_sizes, int n_in,
                              void* d_out, int out_size, void* d_ws, size_t ws_size,
                              hipStream_t stream) {
    const float* x     = (const float*)d_in[0];
    const float* h_q   = (const float*)d_in[1];
    const float* W_inf = (const float*)d_in[2];
    const float* W_att = (const float*)d_in[3];
    const int*   subj  = (const int*)d_in[4];
    const int*   rel   = (const int*)d_in[5];
    const int*   obj   = (const int*)d_in[6];
    float* out = (float*)d_out;

    const size_t NEB = (size_t)N_E * B;           // 6.4e6 floats
    float* bufA = (float*)d_ws;
    float* bufB = bufA + NEB;
    float* rT   = bufB + NEB;                     // 3 * N_R * B floats
    float* a_w  = rT + 3 * N_R * B;               // 3 * B floats

    const int TB  = 3125;    // N_E / 64
    const int HB  = (N_T * 32) / 256;  // 125000

    // x -> xT (transposed)
    k_transpose_in<<<TB, 256, 0, stream>>>(x, bufA);

    // relation / attention chain (tiny, sequential)
    k_r0 <<<32, 256, 0, stream>>>(h_q, W_inf, rT);
    k_r12<<<32, 256, 0, stream>>>(W_inf, rT, rT, rT + N_R * B, 0);
    k_r12<<<32, 256, 0, stream>>>(W_inf, rT, rT + N_R * B, rT + 2 * N_R * B, 1);
    k_att<<<1, 32, 0, stream>>>(h_q, W_att, rT, rT + N_R * B, a_w);

    // hop 0: bufA -> bufB, out = a0 * x1
    hipMemsetAsync(bufB, 0, NEB * sizeof(float), stream);
    k_hop <<<HB, 256, 0, stream>>>(bufA, rT, subj, rel, obj, bufB);
    k_axpy<<<TB, 256, 0, stream>>>(bufB, a_w, 0, out, 1);

    // hop 1: bufB -> bufA, out += a1 * x2
    hipMemsetAsync(bufA, 0, NEB * sizeof(float), stream);
    k_hop <<<HB, 256, 0, stream>>>(bufB, rT + N_R * B, subj, rel, obj, bufA);
    k_axpy<<<TB, 256, 0, stream>>>(bufA, a_w, 1, out, 0);

    // hop 2: bufA -> bufB, out += a2 * x3
    hipMemsetAsync(bufB, 0, NEB * sizeof(float), stream);
    k_hop <<<HB, 256, 0, stream>>>(bufA, rT + 2 * N_R * B, subj, rel, obj, bufB);
    k_axpy<<<TB, 256, 0, stream>>>(bufB, a_w, 2, out, 0);
}

// Round 2
// 405.525 us; speedup vs baseline: 1.1050x; 1.1050x over previous
//
#include <hip/hip_runtime.h>

#define N_R   256
#define N_HOP 3
#define N_E   200000
#define N_T   1000000
#define B     32
#define D_Q   768
#define D_IN  1280   // D_Q + 2*N_R

// ---------------------------------------------------------------------------
// init: transpose x (B,N_E)->xT (N_E,B); flagA[e] = any_b(x[b,e]!=0);
// zero bufB, flagB, counters[3].
// ---------------------------------------------------------------------------
__global__ void k_init(const float* __restrict__ x, float* __restrict__ xT,
                       unsigned char* __restrict__ flagA,
                       float* __restrict__ bufB, unsigned char* __restrict__ flagB,
                       int* __restrict__ counters) {
    __shared__ float tile[64 * 33];
    int e0 = blockIdx.x * 64;
    int t  = threadIdx.x;
#pragma unroll
    for (int i = 0; i < 8; ++i) {
        int o = i * 256 + t;
        int b = o >> 6, e = o & 63;           // coalesced read per x row
        tile[e * 33 + b] = x[b * N_E + e0 + e];
    }
    __syncthreads();
#pragma unroll
    for (int i = 0; i < 8; ++i) {
        int o = i * 256 + t;
        int e = o >> 5, b = o & 31;           // contiguous xT write
        xT[(e0 + e) * 32 + b] = tile[e * 33 + b];
    }
    if (t < 64) {
        unsigned char f = 0;
        for (int b = 0; b < 32; ++b) f |= (tile[t * 33 + b] != 0.f);
        flagA[e0 + t] = f;
    }
    float4 z = {0.f, 0.f, 0.f, 0.f};
    ((float4*)bufB)[blockIdx.x * 512 + t]       = z;
    ((float4*)bufB)[blockIdx.x * 512 + 256 + t] = z;
    if (t < 16) ((unsigned int*)(flagB + e0))[t] = 0u;
    if (blockIdx.x == 0 && t < 3) counters[t] = 0;
}

// ---------------------------------------------------------------------------
// r0[rel,b] = W_inf[rel,0:768] . h_q[b,:]  — one rel per block, 256 threads.
// ---------------------------------------------------------------------------
__global__ void k_r0(const float* __restrict__ h_q, const float* __restrict__ W_inf,
                     float* __restrict__ rT0) {
    __shared__ float hs[32 * 257];
    __shared__ float red[256];
    int t = threadIdx.x, rel = blockIdx.x;
    int b = t & 31, kp = t >> 5;
    float acc = 0.f;
    for (int c = 0; c < 3; ++c) {
        __syncthreads();
#pragma unroll
        for (int i = 0; i < 32; ++i)
            hs[i * 257 + t] = h_q[i * D_Q + c * 256 + t];
        __syncthreads();
        const float* w = &W_inf[rel * D_IN + c * 256 + kp * 32];
#pragma unroll
        for (int i = 0; i < 32; ++i)
            acc += w[i] * hs[b * 257 + kp * 32 + i];
    }
    red[t] = acc;
    __syncthreads();
    if (t < 32) {
        float s = 0.f;
        for (int q = 0; q < 8; ++q) s += red[q * 32 + t];
        rT0[rel * 32 + t] = s;
    }
}

// ---------------------------------------------------------------------------
// r_h = r0(base) + W[:,768:1024]@rPrev (+ W[:,1024:1280]@r0 if hop2)
// ---------------------------------------------------------------------------
__global__ void k_r12(const float* __restrict__ W_inf, const float* __restrict__ rT0,
                      const float* __restrict__ rPrev, float* __restrict__ rOut,
                      int hop2) {
    __shared__ float red[256];
    int t = threadIdx.x, rel = blockIdx.x;
    int b = t & 31, jp = t >> 5;
    const float* w2 = &W_inf[rel * D_IN + D_Q];
    float acc = 0.f;
#pragma unroll 8
    for (int jj = 0; jj < 32; ++jj) {
        int j = jp * 32 + jj;
        acc += w2[j] * rPrev[j * 32 + b];
    }
    if (hop2) {
        const float* w3 = w2 + N_R;
#pragma unroll 8
        for (int jj = 0; jj < 32; ++jj) {
            int j = jp * 32 + jj;
            acc += w3[j] * rT0[j * 32 + b];
        }
    }
    red[t] = acc;
    __syncthreads();
    if (t < 32) {
        float s = rT0[rel * 32 + t];
        for (int q = 0; q < 8; ++q) s += red[q * 32 + t];
        rOut[rel * 32 + t] = s;
    }
}

// ---------------------------------------------------------------------------
// attention scores + softmax -> a_w[hop*32+b]
// ---------------------------------------------------------------------------
__global__ void k_att(const float* __restrict__ h_q, const float* __restrict__ W_att,
                      const float* __restrict__ rT0, const float* __restrict__ rT1,
                      float* __restrict__ a_w) {
    __shared__ float p0[256], p1[256], p2[256], p3[256];
    int t = threadIdx.x;
    int b = t & 31, p = t >> 5;
    float c0 = 0.f;
    for (int k = p * 96; k < p * 96 + 96; ++k) c0 += W_att[k] * h_q[b * D_Q + k];
    float s1 = 0.f, s2 = 0.f, s3 = 0.f;
    for (int j = p * 32; j < p * 32 + 32; ++j) {
        float w2 = W_att[D_Q + j], w3 = W_att[D_Q + N_R + j];
        float r0v = rT0[j * 32 + b], r1v = rT1[j * 32 + b];
        s1 += w2 * r0v; s2 += w2 * r1v; s3 += w3 * r0v;
    }
    p0[t] = c0; p1[t] = s1; p2[t] = s2; p3[t] = s3;
    __syncthreads();
    if (t < 32) {
        float C0 = 0.f, S1 = 0.f, S2 = 0.f, S3 = 0.f;
        for (int q = 0; q < 8; ++q) {
            C0 += p0[q * 32 + t]; S1 += p1[q * 32 + t];
            S2 += p2[q * 32 + t]; S3 += p3[q * 32 + t];
        }
        float c1 = C0 + S1, c2 = C0 + S2 + S3;
        float m  = fmaxf(C0, fmaxf(c1, c2));
        float e0 = __expf(C0 - m), e1 = __expf(c1 - m), e2 = __expf(c2 - m);
        float inv = 1.f / (e0 + e1 + e2);
        a_w[t] = e0 * inv; a_w[32 + t] = e1 * inv; a_w[64 + t] = e2 * inv;
    }
}

// ---------------------------------------------------------------------------
// compact: wl <- triples whose subject is active (flag!=0). 4 triples/thread,
// wave-aggregated atomic append.
// ---------------------------------------------------------------------------
__global__ void k_compact(const int* __restrict__ subj, const unsigned char* __restrict__ flag,
                          int* __restrict__ wl, int* __restrict__ cnt) {
    int t = blockIdx.x * 256 + threadIdx.x;
    int base = t * 4;
    int act[4];
    int k = 0;
    if (base < N_T) {
        int4 s4 = ((const int4*)subj)[t];
        int ss[4] = {s4.x, s4.y, s4.z, s4.w};
#pragma unroll
        for (int i = 0; i < 4; ++i)
            if (flag[ss[i]]) act[k++] = base + i;
    }
    // wave-wide inclusive scan of k
    int lane = threadIdx.x & 63;
    int sc = k;
    for (int off = 1; off < 64; off <<= 1) {
        int n = __shfl_up(sc, off);
        if (lane >= off) sc += n;
    }
    int total = __shfl(sc, 63);
    int basepos = 0;
    if (lane == 63 && total) basepos = atomicAdd(cnt, total);
    basepos = __shfl(basepos, 63);
    int pos = basepos + sc - k;
    for (int i = 0; i < k; ++i) wl[pos + i] = act[i];
}

// ---------------------------------------------------------------------------
// hop over compacted worklist: 32-lane group per active triple.
// xN[obj,b] += xT[subj,b]*rT[rel,b]; set flagOut[obj]=1 (one lane).
// ---------------------------------------------------------------------------
__global__ void k_hop(const float* __restrict__ xT, const float* __restrict__ rT,
                      const int* __restrict__ subj, const int* __restrict__ rel,
                      const int* __restrict__ obj,
                      const int* __restrict__ wl, const int* __restrict__ cnt,
                      float* __restrict__ xN, unsigned char* __restrict__ flagOut,
                      int setFlag) {
    int n = *cnt;
    int gid = (blockIdx.x * 256 + threadIdx.x) >> 5;
    int b   = threadIdx.x & 31;
    int lane64 = threadIdx.x & 63;
    int nGroups = (gridDim.x * 256) >> 5;
    for (int w = gid; w < n; w += nGroups) {
        int t = wl[w];
        int s = subj[t];
        float v = xT[s * 32 + b];
        unsigned long long m = __ballot(v != 0.f);
        unsigned long long half = (lane64 < 32) ? (m & 0xFFFFFFFFull)
                                                : ((m >> 32) << 32);
        if (half) {
            int o = obj[t];
            float rv = rT[rel[t] * 32 + b];
            if (v != 0.f) unsafeAtomicAdd(&xN[o * 32 + b], v * rv);
            if (setFlag) {
                int first = __ffsll((long long)half) - 1;
                if (lane64 == first) flagOut[o] = 1;
            }
        }
    }
}

// ---------------------------------------------------------------------------
// out(B,N_E) (+)= a[hop,b] * xT(N_E,B); optionally zero next hop's buffers.
// ---------------------------------------------------------------------------
__global__ void k_axpy(const float* __restrict__ xT, const float* __restrict__ a_w,
                       int hop, float* __restrict__ out, int store,
                       float* __restrict__ zeroBuf, unsigned char* __restrict__ zeroFlag) {
    __shared__ float tile[32 * 65];
    int e0 = blockIdx.x * 64;
    int t  = threadIdx.x;
#pragma unroll
    for (int i = 0; i < 8; ++i) {
        int o = i * 256 + t;
        int e = o >> 5, b = o & 31;   // contiguous read of xT
        tile[b * 65 + e] = xT[(e0 + e) * 32 + b];
    }
    __syncthreads();
#pragma unroll
    for (int i = 0; i < 8; ++i) {
        int o = i * 256 + t;
        int b = o >> 6, e = o & 63;   // coalesced write per out row segment
        float v = a_w[hop * 32 + b] * tile[b * 65 + e];
        int oi = b * N_E + e0 + e;
        if (store) out[oi] = v;
        else       out[oi] += v;
    }
    if (zeroBuf) {
        float4 z = {0.f, 0.f, 0.f, 0.f};
        ((float4*)zeroBuf)[blockIdx.x * 512 + t]       = z;
        ((float4*)zeroBuf)[blockIdx.x * 512 + 256 + t] = z;
        if (t < 16) ((unsigned int*)(zeroFlag + e0))[t] = 0u;
    }
}

extern "C" void kernel_launch(void* const* d_in, const int* in_sizes, int n_in,
                              void* d_out, int out_size, void* d_ws, size_t ws_size,
                              hipStream_t stream) {
    const float* x     = (const float*)d_in[0];
    const float* h_q   = (const float*)d_in[1];
    const float* W_inf = (const float*)d_in[2];
    const float* W_att = (const float*)d_in[3];
    const int*   subj  = (const int*)d_in[4];
    const int*   rel   = (const int*)d_in[5];
    const int*   obj   = (const int*)d_in[6];
    float* out = (float*)d_out;

    const size_t NEB = (size_t)N_E * B;  // 6.4e6
    float* bufA = (float*)d_ws;
    float* bufB = bufA + NEB;
    int*   wl   = (int*)(bufB + NEB);                    // 1M ints
    float* rT   = (float*)(wl + N_T);                    // 3*N_R*B
    float* a_w  = rT + 3 * N_R * B;
    int*   counters = (int*)(a_w + 96);                  // 3, padded
    unsigned char* flagA = (unsigned char*)(counters + 64);
    unsigned char* flagB = flagA + 204800;

    const int TB = N_E / 64;             // 3125
    const int CB = (N_T / 4 + 255) / 256; // 977
    const int HOPB = 2048;

    k_init<<<TB, 256, 0, stream>>>(x, bufA, flagA, bufB, flagB, counters);

    k_r0 <<<N_R, 256, 0, stream>>>(h_q, W_inf, rT);
    k_r12<<<N_R, 256, 0, stream>>>(W_inf, rT, rT, rT + N_R * B, 0);
    k_r12<<<N_R, 256, 0, stream>>>(W_inf, rT, rT + N_R * B, rT + 2 * N_R * B, 1);
    k_att<<<1, 256, 0, stream>>>(h_q, W_att, rT, rT + N_R * B, a_w);

    // hop 0: bufA -> bufB (flagB), out = a0*x1; zero bufA+flagA for hop1 out
    k_compact<<<CB, 256, 0, stream>>>(subj, flagA, wl, counters + 0);
    k_hop    <<<HOPB, 256, 0, stream>>>(bufA, rT, subj, rel, obj, wl, counters + 0,
                                        bufB, flagB, 1);
    k_axpy   <<<TB, 256, 0, stream>>>(bufB, a_w, 0, out, 1, bufA, flagA);

    // hop 1: bufB -> bufA (flagA), out += a1*x2; zero bufB+flagB for hop2 out
    k_compact<<<CB, 256, 0, stream>>>(subj, flagB, wl, counters + 1);
    k_hop    <<<HOPB, 256, 0, stream>>>(bufB, rT + N_R * B, subj, rel, obj, wl,
                                        counters + 1, bufA, flagA, 1);
    k_axpy   <<<TB, 256, 0, stream>>>(bufA, a_w, 1, out, 0, bufB, flagB);

    // hop 2: bufA -> bufB, out += a2*x3 (no flags needed)
    k_compact<<<CB, 256, 0, stream>>>(subj, flagA, wl, counters + 2);
    k_hop    <<<HOPB, 256, 0, stream>>>(bufA, rT + 2 * N_R * B, subj, rel, obj, wl,
                                        counters + 2, bufB, (unsigned char*)0, 0);
    k_axpy   <<<TB, 256, 0, stream>>>(bufB, a_w, 2, out, 0, (float*)0, (unsigned char*)0);
}